// Round 8
// baseline (12270.614 us; speedup 1.0000x reference)
//
#include <hip/hip_runtime.h>

typedef unsigned short u16;
typedef unsigned int u32;
typedef __bf16 bf16x8 __attribute__((ext_vector_type(8)));
typedef float f32x4 __attribute__((ext_vector_type(4)));

#define NB 16
#define CIN 26
#define IMH 96
#define IMW 72
#define HW6912 6912      // 96*72
#define NPIX 110592      // 16*6912
// big padded geom (h1, feeds dilated convs up to dil=24)
#define BPH 144
#define BPW 120
#define BPAD 24
// small padded geom (x0, h0: only 3x3 dil=1 consumers)
#define SPH 98
#define SPW 74
#define SPAD 1

__device__ __forceinline__ float b2f(u16 h) {
    union { u32 u; float f; } x; x.u = ((u32)h) << 16; return x.f;
}
__device__ __forceinline__ u16 f2b(float f) {
    union { float f; u32 u; } x; x.f = f;
    u32 u = x.u;
    u32 r = (u + 0x7fffu + ((u >> 16) & 1u)) >> 16;
    return (u16)r;
}
// dtype-agnostic input load: element i of array p, fp32 if f else bf16
__device__ __forceinline__ float ldin(const void* p, int i, int f) {
    return f ? ((const float*)p)[i] : b2f(((const u16*)p)[i]);
}

// map flat pixel m -> element offset in padded NHWC buffer
__device__ __forceinline__ int pbase(int m, int ph, int pw, int pad, int clog2) {
    int b = m / HW6912;
    int p = m - b * HW6912;
    int y = p / IMW;
    int x = p - y * IMW;
    return (((b * ph + y + pad) * pw) + (x + pad)) << clog2;
}

// ---------------------------------------------------------------- dtype probe
__global__ void probe_kernel(const void* bn, int* flag) {
    if (threadIdx.x == 0 && blockIdx.x == 0) {
        const float* f = (const float*)bn;
        int cnt = 0;
        for (int j = 64; j < 128; ++j) {
            float v = f[j];
            if (v >= 0.4f && v <= 1.6f) cnt++;   // NaN fails both -> not counted
        }
        *flag = (cnt >= 32) ? 1 : 0;
    }
}

// ---------------------------------------------------------------- zero
__global__ __launch_bounds__(256) void zero_ws_kernel(uint4* p, int n16) {
    int i = blockIdx.x * 256 + threadIdx.x;
    int stride = gridDim.x * 256;
    for (; i < n16; i += stride) p[i] = make_uint4(0u, 0u, 0u, 0u);
}

// ---------------------------------------------------------------- x0 = ref - sup -> small padded NHWC(32) bf16
__global__ __launch_bounds__(256) void fill_x0_kernel(const void* __restrict__ ref,
                                                      const void* __restrict__ sup,
                                                      u16* __restrict__ x0,
                                                      const int* __restrict__ flag) {
    int f = *flag;
    int t = blockIdx.x * 256 + threadIdx.x;   // 110592 threads
    int b = t / HW6912;
    int p = t - b * HW6912;
    int y = p / IMW;
    int x = p - y * IMW;
    int dst = ((b * SPH + y + SPAD) * SPW + (x + SPAD)) << 5;
    #pragma unroll 1
    for (int c = 0; c < CIN; ++c) {
        int src = (b * CIN + c) * HW6912 + p;
        x0[dst + c] = f2b(ldin(ref, src, f) - ldin(sup, src, f));
    }
}

// ---------------------------------------------------------------- weight preps
__global__ __launch_bounds__(256) void prep_rest_kernel(const void* __restrict__ w1r,
                                                        const void* __restrict__ w2r,
                                                        const void* __restrict__ bn1r,
                                                        const void* __restrict__ bn2r,
                                                        u16* __restrict__ dst,
                                                        const int* __restrict__ flag) {
    int f = *flag;
    int idx = blockIdx.x * 256 + threadIdx.x;        // 38*147456
    int c = idx / 147456;
    int rem = idx - c * 147456;
    int o = rem / 1152;
    int k = rem - o * 1152;
    int s = k >> 7, ci = k & 127;
    const void* w  = (c < 19) ? w1r : w2r;
    int wb         = (c < 19) ? c * 147456 : (c - 19) * 147456;
    const void* bn = (c < 19) ? bn1r : bn2r;
    int bb         = ((c < 19) ? c : (c - 19)) * 512;
    float inv = ldin(bn, bb + o, f) * rsqrtf(ldin(bn, bb + 384 + o, f) + 1e-5f);
    dst[idx] = f2b(ldin(w, wb + (o * 128 + ci) * 9 + s, f) * inv);
}

__global__ __launch_bounds__(256) void prep_b0_kernel(const void* __restrict__ w1_0,
                                                      const void* __restrict__ w2_0,
                                                      const void* __restrict__ wd_0,
                                                      const void* __restrict__ bn1_0,
                                                      const void* __restrict__ bn2_0,
                                                      const void* __restrict__ bnd_0,
                                                      u16* __restrict__ W20,
                                                      u16* __restrict__ W10,
                                                      u16* __restrict__ Wd,
                                                      const int* __restrict__ flag) {
    int f = *flag;
    int idx = blockIdx.x * 256 + threadIdx.x;  // 188416
    if (idx < 147456) {
        int o = idx / 1152, k = idx - o * 1152;
        int s = k >> 7, ci = k & 127;
        float inv = ldin(bn2_0, o, f) * rsqrtf(ldin(bn2_0, 384 + o, f) + 1e-5f);
        W20[idx] = f2b(ldin(w2_0, (o * 128 + ci) * 9 + s, f) * inv);
    } else if (idx < 184320) {
        int j = idx - 147456;
        int o = j / 288, k = j - o * 288;
        int s = k >> 5, ci = k & 31;
        float inv = ldin(bn1_0, o, f) * rsqrtf(ldin(bn1_0, 384 + o, f) + 1e-5f);
        W10[j] = (ci < CIN) ? f2b(ldin(w1_0, (o * CIN + ci) * 9 + s, f) * inv) : (u16)0;
    } else {
        int j = idx - 184320;
        int o = j >> 5, ci = j & 31;
        float inv = ldin(bnd_0, o, f) * rsqrtf(ldin(bnd_0, 384 + o, f) + 1e-5f);
        Wd[j] = (ci < CIN) ? f2b(ldin(wd_0, o * CIN + ci, f) * inv) : (u16)0;
    }
}

__global__ __launch_bounds__(256) void prep_off_kernel(const void* __restrict__ offw,
                                                       u16* __restrict__ dst,
                                                       const int* __restrict__ flag) {
    int f = *flag;
    int idx = blockIdx.x * 256 + threadIdx.x;    // 5*512*1152
    int d = idx / 589824;
    int rem = idx - d * 589824;
    int n = rem / 1152;
    int k = rem - n * 1152;
    int s = k >> 7, ci = k & 127;
    dst[idx] = (n < 468) ? f2b(ldin(offw, ((d * 468 + n) * 128 + ci) * 9 + s, f)) : (u16)0;
}

__global__ __launch_bounds__(256) void prep_bias_kernel(const void* __restrict__ bn1_0,
                                                        const void* __restrict__ bn2_0,
                                                        const void* __restrict__ bnd_0,
                                                        const void* __restrict__ bn1r,
                                                        const void* __restrict__ bn2r,
                                                        float* __restrict__ dst,
                                                        const int* __restrict__ flag) {
    int f = *flag;
    int idx = blockIdx.x * 256 + threadIdx.x;
    if (idx >= 41 * 128) return;
    int set = idx >> 7;
    int o = idx & 127;
    const void* bn; int bb = 0;
    if (set == 0) bn = bn1_0;
    else if (set == 1) bn = bn2_0;
    else if (set == 2) bn = bnd_0;
    else if (set < 22) { bn = bn1r; bb = (set - 3) * 512; }
    else { bn = bn2r; bb = (set - 22) * 512; }
    float s = ldin(bn, bb + o, f), b = ldin(bn, bb + 128 + o, f);
    float mu = ldin(bn, bb + 256 + o, f), v = ldin(bn, bb + 384 + o, f);
    float inv = s * rsqrtf(v + 1e-5f);
    dst[idx] = b - mu * inv;
}

// ---------------------------------------------------------------- implicit-GEMM conv, LDS-free
// Tile 128x64, BK=32. Each wave computes 64 rows x 32 cols; fragments loaded
// global->VGPR directly (global_load_dwordx4): NO LDS, NO barrier in the K-loop.
// Waves drift independently; latency hidden by wave TLP + compiler load/MFMA
// interleave (hipBLASLt-style restructured K-loop, per guide s02/m131 notes).
// XCD swizzle: wg%8 = XCD; each XCD gets a contiguous 1/8 of the M-tiles so its
// A working set (~3.5 MB) fits the per-XCD 4 MB L2.
__global__ __launch_bounds__(256, 4) void conv_gemm(const u16* __restrict__ A,
                                                    const u16* __restrict__ W,
                                                    const float* __restrict__ bias,
                                                    const u16* __restrict__ idn,
                                                    u16* __restrict__ out,
                                                    int clog2, int nslab, int K, int dil,
                                                    int aph, int apw, int apad,
                                                    int Nvalid, int outC, int out_mode, int flags,
                                                    int m_base, int tm) {
    int tid = threadIdx.x;
    int wg = blockIdx.x;
    int pxm = tm >> 3;               // m-tiles per XCD (tm divisible by 8)
    int xcd = wg & 7;
    int jj = wg >> 3;
    int mt = xcd * pxm + jj % pxm;
    int nt = jj / pxm;
    int m0 = mt * 128;
    int n0 = nt * 64;
    int Cin = 1 << clog2;

    int wid = tid >> 6;
    int lane = tid & 63;
    int lr = lane & 15;
    int lq = lane >> 4;
    int wm = (wid >> 1) * 64;
    int wn = (wid & 1) * 32;

    // per-lane loop-invariant base offsets (u16 elements)
    int abase[4];
    #pragma unroll
    for (int i = 0; i < 4; ++i)
        abase[i] = pbase(m_base + m0 + wm + i * 16 + lr, aph, apw, apad, clog2) + lq * 8;
    const u16* brow0 = W + (n0 + wn + lr) * K + lq * 8;
    const u16* brow1 = W + (n0 + wn + 16 + lr) * K + lq * 8;

    f32x4 acc[4][2];
    #pragma unroll
    for (int i = 0; i < 4; ++i)
        #pragma unroll
        for (int j = 0; j < 2; ++j)
            acc[i][j] = (f32x4){0.f, 0.f, 0.f, 0.f};

    int nk = K >> 5;
    #pragma unroll 2
    for (int it = 0; it < nk; ++it) {
        int kt = it << 5;
        int sl = kt >> clog2;
        int win = kt & (Cin - 1);
        int soff = 0;
        if (nslab == 9) {
            int d3 = sl / 3;
            soff = (((d3 - 1) * apw + (sl - d3 * 3 - 1)) * dil) << clog2;
        }
        bf16x8 af[4], bfr[2];
        #pragma unroll
        for (int i = 0; i < 4; ++i)
            af[i] = *(const bf16x8*)(A + abase[i] + soff + win);
        bfr[0] = *(const bf16x8*)(brow0 + kt);
        bfr[1] = *(const bf16x8*)(brow1 + kt);
        #pragma unroll
        for (int i = 0; i < 4; ++i)
            #pragma unroll
            for (int j = 0; j < 2; ++j)
                acc[i][j] = __builtin_amdgcn_mfma_f32_16x16x32_bf16(af[i], bfr[j], acc[i][j], 0, 0, 0);
    }

    int relu = flags & 1;
    #pragma unroll
    for (int i = 0; i < 4; ++i) {
        #pragma unroll
        for (int r = 0; r < 4; ++r) {
            int ml = m0 + wm + i * 16 + lq * 4 + r;
            int ob, ib = 0;
            if (out_mode == 0) {
                ob = ml * outC;
            } else if (out_mode == 1) {
                ob = pbase(m_base + ml, SPH, SPW, SPAD, 7);
            } else {
                ob = pbase(m_base + ml, BPH, BPW, BPAD, 7);
                ib = ob;
            }
            #pragma unroll
            for (int j = 0; j < 2; ++j) {
                int n = n0 + wn + j * 16 + lr;
                float v = acc[i][j][r];
                if (bias) v += bias[n];
                if (idn) v += b2f(idn[ib + n]);
                if (relu) v = fmaxf(v, 0.f);
                if (n < Nvalid) out[ob + n] = f2b(v);
            }
        }
    }
}

// ---------------------------------------------------------------- deformable conv (one dilation, one chunk)
// 256 threads = 64 pixels x 4 channel-groups; LDS tree-reduce across groups.
template <int F>
__device__ __forceinline__ float dsamp2(const void* sup, int base, int yi, int xi) {
    bool ok = (yi >= 0) & (yi < IMH) & (xi >= 0) & (xi < IMW);
    int yc = yi < 0 ? 0 : (yi > IMH - 1 ? IMH - 1 : yi);
    int xc = xi < 0 ? 0 : (xi > IMW - 1 ? IMW - 1 : xi);
    float v = F ? ((const float*)sup)[base + yc * IMW + xc]
                : b2f(((const u16*)sup)[base + yc * IMW + xc]);
    return ok ? v : 0.f;
}

template <int F>
__device__ __forceinline__ void deform_body(const void* __restrict__ sup,
                                            const u16* __restrict__ oc,
                                            const float* __restrict__ wsm,
                                            f32x4 acc[7],
                                            int c0, int c1, int b, int y, int x, int dil) {
    #pragma unroll 1
    for (int c = c0; c < c1; ++c) {
        int ibase = (b * CIN + c) * HW6912;
        #pragma unroll
        for (int t = 0; t < 9; ++t) {
            u32 pr = *(const u32*)(oc + c * 18 + t * 2);
            float dy = b2f((u16)(pr & 0xffffu));
            float dx = b2f((u16)(pr >> 16));
            float py = (float)(y + (t / 3 - 1) * dil) + dy;
            float px = (float)(x + (t % 3 - 1) * dil) + dx;
            float y0f = floorf(py), x0f = floorf(px);
            float ly = py - y0f, lx = px - x0f;
            int y0 = (int)y0f, x0 = (int)x0f;
            float v00 = dsamp2<F>(sup, ibase, y0, x0);
            float v01 = dsamp2<F>(sup, ibase, y0, x0 + 1);
            float v10 = dsamp2<F>(sup, ibase, y0 + 1, x0);
            float v11 = dsamp2<F>(sup, ibase, y0 + 1, x0 + 1);
            float val = (v00 * (1.f - lx) + v01 * lx) * (1.f - ly)
                      + (v10 * (1.f - lx) + v11 * lx) * ly;
            const float4* wr = (const float4*)&wsm[(c * 9 + t) * 28];
            #pragma unroll
            for (int u = 0; u < 7; ++u) {
                float4 w4 = wr[u];
                acc[u][0] = fmaf(val, w4.x, acc[u][0]);
                acc[u][1] = fmaf(val, w4.y, acc[u][1]);
                acc[u][2] = fmaf(val, w4.z, acc[u][2]);
                acc[u][3] = fmaf(val, w4.w, acc[u][3]);
            }
        }
    }
}

__global__ __launch_bounds__(256) void deform_kernel(const void* __restrict__ sup,
                                                     const u16* __restrict__ offb,   // [m_local][468] bf16
                                                     const void* __restrict__ dwall, // [5][26][26][9]
                                                     int dwoff,
                                                     float* __restrict__ accws,      // [m][32]
                                                     int dil, int first, int m_base,
                                                     const int* __restrict__ flag) {
    int f = *flag;
    __shared__ float wsm[26 * 9 * 28];   // [c][t][o<28]
    __shared__ float red[4 * 64 * 27];   // [cg][px][o pad27]
    int tid = threadIdx.x;
    for (int i = tid; i < 26 * 9 * 28; i += 256) {
        int o = i % 28;
        int ct = i / 28;
        int c = ct / 9, t = ct - c * 9;
        wsm[i] = (o < CIN) ? ldin(dwall, dwoff + (o * CIN + c) * 9 + t, f) : 0.f;
    }
    __syncthreads();

    int px = tid & 63;
    int cg = tid >> 6;
    int c0 = (cg * 26) >> 2;         // 0,6,13,19
    int c1 = ((cg + 1) * 26) >> 2;   // 6,13,19,26
    int ml = blockIdx.x * 64 + px;
    int m = m_base + ml;
    int b = m / HW6912;
    int p = m - b * HW6912;
    int y = p / IMW;
    int x = p - y * IMW;

    f32x4 acc[7];
    #pragma unroll
    for (int u = 0; u < 7; ++u) acc[u] = (f32x4){0.f, 0.f, 0.f, 0.f};

    const u16* oc = offb + (size_t)ml * 468;
    if (f) deform_body<1>(sup, oc, wsm, acc, c0, c1, b, y, x, dil);
    else   deform_body<0>(sup, oc, wsm, acc, c0, c1, b, y, x, dil);

    float* myred = red + tid * 27;
    #pragma unroll
    for (int u = 0; u < 7; ++u) {
        #pragma unroll
        for (int k2 = 0; k2 < 4; ++k2) {
            int o = u * 4 + k2;
            if (o < 26) myred[o] = acc[u][k2];
        }
    }
    __syncthreads();

    int base_m = m_base + blockIdx.x * 64;
    for (int v = tid; v < 64 * 26; v += 256) {
        int ppx = v / 26;
        int o = v - ppx * 26;
        float s = red[ppx * 27 + o] + red[(64 + ppx) * 27 + o]
                + red[(128 + ppx) * 27 + o] + red[(192 + ppx) * 27 + o];
        size_t ai = (size_t)(base_m + ppx) * 32 + o;
        if (first) accws[ai] = s;
        else       accws[ai] += s;
    }
}

// ---------------------------------------------------------------- finalize: accws[m][32] -> out NCHW (dtype per flag), /5
__global__ __launch_bounds__(256) void finalize_kernel(const float* __restrict__ accws,
                                                       void* __restrict__ out,
                                                       const int* __restrict__ flag) {
    int f = *flag;
    int q = blockIdx.x * 256 + threadIdx.x;     // 16*26*6912
    int b = q / (CIN * HW6912);
    int r = q - b * (CIN * HW6912);
    int o = r / HW6912;
    int p = r - o * HW6912;
    float v = accws[(size_t)(b * HW6912 + p) * 32 + o] * 0.2f;
    if (f) ((float*)out)[q] = v;
    else   ((u16*)out)[q] = f2b(v);
}

// ---------------------------------------------------------------- host
extern "C" void kernel_launch(void* const* d_in, const int* in_sizes, int n_in,
                              void* d_out, int out_size, void* d_ws, size_t ws_size,
                              hipStream_t stream) {
    (void)in_sizes; (void)n_in; (void)out_size;
    const void* ref_x    = d_in[0];
    const void* sup_x    = d_in[1];
    const void* w1_0     = d_in[2];
    const void* w2_0     = d_in[3];
    const void* wd_0     = d_in[4];
    const void* bn1_0    = d_in[5];
    const void* bn2_0    = d_in[6];
    const void* bnd_0    = d_in[7];
    const void* w1_rest  = d_in[8];
    const void* w2_rest  = d_in[9];
    const void* bn1_rest = d_in[10];
    const void* bn2_rest = d_in[11];
    const void* offset_w = d_in[12];
    const void* deform_w = d_in[13];

    // workspace layout (bytes)
    size_t o_x0    = 0;                          // 16*98*74*32*2   =  7,426,048
    size_t o_h0    = o_x0 + 7426048;             // 16*98*74*128*2  = 29,704,192  (offb chunk aliases this)
    size_t o_h1    = o_h0 + 29704192;            // 16*144*120*128*2= 70,778,880
    size_t o_acc   = o_h1 + 70778880;            // 110592*32*4     = 14,155,776
    size_t o_wrest = o_acc + 14155776;           // 38*128*1152*2   = 11,206,656
    size_t o_w20   = o_wrest + 11206656;         // 128*1152*2      =    294,912
    size_t o_w10   = o_w20 + 294912;             // 128*288*2       =     73,728
    size_t o_wd    = o_w10 + 73728;              // 128*32*2        =      8,192
    size_t o_woff  = o_wd + 8192;                // 5*512*1152*2    =  5,898,240
    size_t o_bias  = o_woff + 5898240;           // 41*128*4        =     20,992
    size_t o_flag  = o_bias + 20992;             // 64
    size_t o_end   = o_flag + 64;                // total 139,567,680
    if (ws_size < o_end) return;   // clean validation failure instead of a memory fault

    char* ws = (char*)d_ws;
    u16* x0    = (u16*)(ws + o_x0);
    u16* h0    = (u16*)(ws + o_h0);
    u16* offb  = (u16*)(ws + o_h0);      // alias: h0 dead once the chain finishes
    u16* h1    = (u16*)(ws + o_h1);
    float* accb = (float*)(ws + o_acc);
    u16* Wr    = (u16*)(ws + o_wrest);
    u16* W20   = (u16*)(ws + o_w20);
    u16* W10   = (u16*)(ws + o_w10);
    u16* Wd    = (u16*)(ws + o_wd);
    u16* Woff  = (u16*)(ws + o_woff);
    float* biasb = (float*)(ws + o_bias);
    int* flagp = (int*)(ws + o_flag);

    dim3 blk(256);

    probe_kernel<<<1, 64, 0, stream>>>(bn1_0, flagp);
    // zero x0 + h0 + h1 (padding halos must be zero); contiguous region
    zero_ws_kernel<<<2048, blk, 0, stream>>>((uint4*)ws, (int)((7426048 + 29704192 + 70778880) / 16));
    fill_x0_kernel<<<432, blk, 0, stream>>>(ref_x, sup_x, x0, flagp);
    prep_rest_kernel<<<21888, blk, 0, stream>>>(w1_rest, w2_rest, bn1_rest, bn2_rest, Wr, flagp);
    prep_b0_kernel<<<736, blk, 0, stream>>>(w1_0, w2_0, wd_0, bn1_0, bn2_0, bnd_0, W20, W10, Wd, flagp);
    prep_off_kernel<<<11520, blk, 0, stream>>>(offset_w, Woff, flagp);
    prep_bias_kernel<<<21, blk, 0, stream>>>(bn1_0, bn2_0, bnd_0, bn1_rest, bn2_rest, biasb, flagp);

    // chain convs: tile 128x64 over M=110592 (tm=864 m-tiles), N=128 (tn=2) -> 1728 blocks, 1-D grid
    int gchain = 1728;
    // block0: downsample (1x1 conv + BN) -> h1 (big geom)
    conv_gemm<<<gchain, blk, 0, stream>>>(x0, Wd, biasb + 2 * 128, nullptr, h1,
                                          5, 1, 32, 1, SPH, SPW, SPAD, 128, 128, 2, 0, 0, 864);
    // block0: conv1 + BN + relu -> h0 (small geom)
    conv_gemm<<<gchain, blk, 0, stream>>>(x0, W10, biasb + 0 * 128, nullptr, h0,
                                          5, 9, 288, 1, SPH, SPW, SPAD, 128, 128, 1, 1, 0, 864);
    // block0: conv2 + BN + idn(h1) + relu -> h1
    conv_gemm<<<gchain, blk, 0, stream>>>(h0, W20, biasb + 1 * 128, h1, h1,
                                          7, 9, 1152, 1, SPH, SPW, SPAD, 128, 128, 2, 1, 0, 864);

    for (int t = 0; t < 19; ++t) {
        const u16* wa = Wr + (size_t)t * 147456;
        const u16* wb = Wr + (size_t)(19 + t) * 147456;
        conv_gemm<<<gchain, blk, 0, stream>>>(h1, wa, biasb + (3 + t) * 128, nullptr, h0,
                                              7, 9, 1152, 1, BPH, BPW, BPAD, 128, 128, 1, 1, 0, 864);
        conv_gemm<<<gchain, blk, 0, stream>>>(h0, wb, biasb + (22 + t) * 128, h1, h1,
                                              7, 9, 1152, 1, SPH, SPW, SPAD, 128, 128, 2, 1, 0, 864);
    }

    // 5 dilation branches, chunked over 4 batches at a time (offb aliases h0: 25.9 MB <= 29.7 MB)
    // offset conv: M=27648 -> tm=216 m-tiles, N=512 -> tn=8 -> 1728 blocks
    const int dils[5] = {3, 6, 12, 18, 24};
    for (int i = 0; i < 5; ++i) {
        for (int cb = 0; cb < 4; ++cb) {
            int mb = cb * 27648;   // 4 batches * 6912
            conv_gemm<<<1728, blk, 0, stream>>>(h1, Woff + (size_t)i * 589824, nullptr, nullptr,
                                                offb, 7, 9, 1152, dils[i], BPH, BPW, BPAD,
                                                468, 468, 0, 0, mb, 216);
            deform_kernel<<<432, blk, 0, stream>>>(sup_x, offb, deform_w, i * 6084, accb,
                                                   dils[i], (i == 0) ? 1 : 0, mb, flagp);
        }
    }
    finalize_kernel<<<11232, blk, 0, stream>>>(accb, d_out, flagp);
}

// Round 9
// 6293.855 us; speedup vs baseline: 1.9496x; 1.9496x over previous
//
#include <hip/hip_runtime.h>

typedef unsigned short u16;
typedef unsigned int u32;
typedef __bf16 bf16x8 __attribute__((ext_vector_type(8)));
typedef float f32x4 __attribute__((ext_vector_type(4)));

#define NB 16
#define CIN 26
#define IMH 96
#define IMW 72
#define HW6912 6912      // 96*72
#define NPIX 110592      // 16*6912
// small padded geom (all internal activations): 98 x 74, pad 1
#define SPH 98
#define SPW 74
#define SPAD 1
// halo tile geometry
#define TLW 136          // elems per column slot (128 ch + 8 pad)
#define TCOLS 82         // cols x = -1 .. 80
#define TROWE (TCOLS * TLW)   // 11152 elems per tile row

__device__ __forceinline__ float b2f(u16 h) {
    union { u32 u; float f; } x; x.u = ((u32)h) << 16; return x.f;
}
__device__ __forceinline__ u16 f2b(float f) {
    union { float f; u32 u; } x; x.f = f;
    u32 u = x.u;
    u32 r = (u + 0x7fffu + ((u >> 16) & 1u)) >> 16;
    return (u16)r;
}
__device__ __forceinline__ float ldin(const void* p, int i, int f) {
    return f ? ((const float*)p)[i] : b2f(((const u16*)p)[i]);
}

// map flat pixel m -> element offset in small padded NHWC buffer, (1<<clog2) ch
__device__ __forceinline__ int pbase(int m, int clog2) {
    int b = m / HW6912;
    int p = m - b * HW6912;
    int y = p / IMW;
    int x = p - y * IMW;
    return (((b * SPH + y + SPAD) * SPW) + (x + SPAD)) << clog2;
}

__device__ __forceinline__ void glds16(const u16* g, u16* l) {
    __builtin_amdgcn_global_load_lds(
        (const __attribute__((address_space(1))) void*)g,
        (__attribute__((address_space(3))) void*)l, 16, 0, 0);
}

// ---------------------------------------------------------------- dtype probe
__global__ void probe_kernel(const void* bn, int* flag) {
    if (threadIdx.x == 0 && blockIdx.x == 0) {
        const float* f = (const float*)bn;
        int cnt = 0;
        for (int j = 64; j < 128; ++j) {
            float v = f[j];
            if (v >= 0.4f && v <= 1.6f) cnt++;
        }
        *flag = (cnt >= 32) ? 1 : 0;
    }
}

// ---------------------------------------------------------------- zero
__global__ __launch_bounds__(256) void zero_ws_kernel(uint4* p, int n16) {
    int i = blockIdx.x * 256 + threadIdx.x;
    int stride = gridDim.x * 256;
    for (; i < n16; i += stride) p[i] = make_uint4(0u, 0u, 0u, 0u);
}

// ---------------------------------------------------------------- x0 = ref - sup -> small padded NHWC(32)
__global__ __launch_bounds__(256) void fill_x0_kernel(const void* __restrict__ ref,
                                                      const void* __restrict__ sup,
                                                      u16* __restrict__ x0,
                                                      const int* __restrict__ flag) {
    int f = *flag;
    int t = blockIdx.x * 256 + threadIdx.x;
    int b = t / HW6912;
    int p = t - b * HW6912;
    int y = p / IMW;
    int x = p - y * IMW;
    int dst = ((b * SPH + y + SPAD) * SPW + (x + SPAD)) << 5;
    #pragma unroll 1
    for (int c = 0; c < CIN; ++c) {
        int src = (b * CIN + c) * HW6912 + p;
        x0[dst + c] = f2b(ldin(ref, src, f) - ldin(sup, src, f));
    }
}

// ---------------------------------------------------------------- weight preps
__global__ __launch_bounds__(256) void prep_rest_kernel(const void* __restrict__ w1r,
                                                        const void* __restrict__ w2r,
                                                        const void* __restrict__ bn1r,
                                                        const void* __restrict__ bn2r,
                                                        u16* __restrict__ dst,
                                                        const int* __restrict__ flag) {
    int f = *flag;
    int idx = blockIdx.x * 256 + threadIdx.x;        // 38*147456
    int c = idx / 147456;
    int rem = idx - c * 147456;
    int o = rem / 1152;
    int k = rem - o * 1152;
    int s = k >> 7, ci = k & 127;
    const void* w  = (c < 19) ? w1r : w2r;
    int wb         = (c < 19) ? c * 147456 : (c - 19) * 147456;
    const void* bn = (c < 19) ? bn1r : bn2r;
    int bb         = ((c < 19) ? c : (c - 19)) * 512;
    float inv = ldin(bn, bb + o, f) * rsqrtf(ldin(bn, bb + 384 + o, f) + 1e-5f);
    dst[idx] = f2b(ldin(w, wb + (o * 128 + ci) * 9 + s, f) * inv);
}

__global__ __launch_bounds__(256) void prep_b0_kernel(const void* __restrict__ w1_0,
                                                      const void* __restrict__ w2_0,
                                                      const void* __restrict__ wd_0,
                                                      const void* __restrict__ bn1_0,
                                                      const void* __restrict__ bn2_0,
                                                      const void* __restrict__ bnd_0,
                                                      u16* __restrict__ W20,
                                                      u16* __restrict__ W10,
                                                      u16* __restrict__ Wd,
                                                      const int* __restrict__ flag) {
    int f = *flag;
    int idx = blockIdx.x * 256 + threadIdx.x;  // 188416
    if (idx < 147456) {
        int o = idx / 1152, k = idx - o * 1152;
        int s = k >> 7, ci = k & 127;
        float inv = ldin(bn2_0, o, f) * rsqrtf(ldin(bn2_0, 384 + o, f) + 1e-5f);
        W20[idx] = f2b(ldin(w2_0, (o * 128 + ci) * 9 + s, f) * inv);
    } else if (idx < 184320) {
        int j = idx - 147456;
        int o = j / 288, k = j - o * 288;
        int s = k >> 5, ci = k & 31;
        float inv = ldin(bn1_0, o, f) * rsqrtf(ldin(bn1_0, 384 + o, f) + 1e-5f);
        W10[j] = (ci < CIN) ? f2b(ldin(w1_0, (o * CIN + ci) * 9 + s, f) * inv) : (u16)0;
    } else {
        int j = idx - 184320;
        int o = j >> 5, ci = j & 31;
        float inv = ldin(bnd_0, o, f) * rsqrtf(ldin(bnd_0, 384 + o, f) + 1e-5f);
        Wd[j] = (ci < CIN) ? f2b(ldin(wd_0, o * CIN + ci, f) * inv) : (u16)0;
    }
}

__global__ __launch_bounds__(256) void prep_off_kernel(const void* __restrict__ offw,
                                                       u16* __restrict__ dst,
                                                       const int* __restrict__ flag) {
    int f = *flag;
    int idx = blockIdx.x * 256 + threadIdx.x;    // 5*512*1152
    int d = idx / 589824;
    int rem = idx - d * 589824;
    int n = rem / 1152;
    int k = rem - n * 1152;
    int s = k >> 7, ci = k & 127;
    dst[idx] = (n < 468) ? f2b(ldin(offw, ((d * 468 + n) * 128 + ci) * 9 + s, f)) : (u16)0;
}

__global__ __launch_bounds__(256) void prep_bias_kernel(const void* __restrict__ bn1_0,
                                                        const void* __restrict__ bn2_0,
                                                        const void* __restrict__ bnd_0,
                                                        const void* __restrict__ bn1r,
                                                        const void* __restrict__ bn2r,
                                                        float* __restrict__ dst,
                                                        const int* __restrict__ flag) {
    int f = *flag;
    int idx = blockIdx.x * 256 + threadIdx.x;
    if (idx >= 41 * 128) return;
    int set = idx >> 7;
    int o = idx & 127;
    const void* bn; int bb = 0;
    if (set == 0) bn = bn1_0;
    else if (set == 1) bn = bn2_0;
    else if (set == 2) bn = bnd_0;
    else if (set < 22) { bn = bn1r; bb = (set - 3) * 512; }
    else { bn = bn2r; bb = (set - 22) * 512; }
    float s = ldin(bn, bb + o, f), b = ldin(bn, bb + 128 + o, f);
    float mu = ldin(bn, bb + 256 + o, f), v = ldin(bn, bb + 384 + o, f);
    float inv = s * rsqrtf(v + 1e-5f);
    dst[idx] = b - mu * inv;
}

// ---------------------------------------------------------------- generic implicit-GEMM conv (R7 structure)
// Used only for the two cheap x0 convs (K=32 / K=288). 128x64 tile, BK=32,
// ping-pong LDS via global_load_lds, one barrier/iter. out: small padded 128ch.
__global__ __launch_bounds__(256) void conv_gemm(const u16* __restrict__ A,
                                                 const u16* __restrict__ W,
                                                 const float* __restrict__ bias,
                                                 u16* __restrict__ out,
                                                 int clog2, int nslab, int K,
                                                 int relu) {
    __shared__ u16 As[2][128 * 32];
    __shared__ u16 Bs[2][64 * 32];
    int tid = threadIdx.x;
    int m0 = blockIdx.x * 128;
    int n0 = blockIdx.y * 64;
    int Cin = 1 << clog2;

    int r0 = tid >> 2;
    int q8 = (tid & 3) * 8;
    int arow0 = pbase(m0 + r0, clog2) + q8;
    int arow1 = pbase(m0 + r0 + 64, clog2) + q8;
    int brow0 = (n0 + r0) * K + q8;
    int l8 = tid * 8;

    f32x4 acc[4][2];
    #pragma unroll
    for (int i = 0; i < 4; ++i)
        #pragma unroll
        for (int j = 0; j < 2; ++j)
            acc[i][j] = (f32x4){0.f, 0.f, 0.f, 0.f};

    int wid = tid >> 6;
    int wm = (wid >> 1) * 64;
    int wn = (wid & 1) * 32;
    int lane = tid & 63;
    int lr = lane & 15;
    int lq = lane >> 4;

    int nk = K >> 5;
    auto stage = [&](int buf, int kt) {
        int sl = kt >> clog2;
        int win = kt & (Cin - 1);
        int soff = 0;
        if (nslab == 9) {
            int d3 = sl / 3;
            soff = (((d3 - 1) * SPW + (sl - d3 * 3 - 1))) << clog2;
        }
        glds16(A + arow0 + soff + win, &As[buf][l8]);
        glds16(A + arow1 + soff + win, &As[buf][2048 + l8]);
        glds16(W + brow0 + kt, &Bs[buf][l8]);
    };

    stage(0, 0);
    #pragma unroll 1
    for (int it = 0; it < nk; ++it) {
        __syncthreads();
        if (it + 1 < nk) stage((it + 1) & 1, (it + 1) << 5);
        const u16* as = As[it & 1];
        const u16* bs = Bs[it & 1];
        bf16x8 af[4], bfr[2];
        #pragma unroll
        for (int i = 0; i < 4; ++i)
            af[i] = *(const bf16x8*)&as[(wm + i * 16 + lr) * 32 + lq * 8];
        #pragma unroll
        for (int j = 0; j < 2; ++j)
            bfr[j] = *(const bf16x8*)&bs[(wn + j * 16 + lr) * 32 + lq * 8];
        #pragma unroll
        for (int i = 0; i < 4; ++i)
            #pragma unroll
            for (int j = 0; j < 2; ++j)
                acc[i][j] = __builtin_amdgcn_mfma_f32_16x16x32_bf16(af[i], bfr[j], acc[i][j], 0, 0, 0);
    }

    #pragma unroll
    for (int i = 0; i < 4; ++i) {
        #pragma unroll
        for (int r = 0; r < 4; ++r) {
            int ml = m0 + wm + i * 16 + lq * 4 + r;
            int ob = pbase(ml, 7);
            #pragma unroll
            for (int j = 0; j < 2; ++j) {
                int n = n0 + wn + j * 16 + lr;
                float v = acc[i][j][r] + bias[n];
                if (relu) v = fmaxf(v, 0.f);
                out[ob + n] = f2b(v);
            }
        }
    }
}

// ---------------------------------------------------------------- halo-LDS chain conv (dil=1, 128ch in, 128ch out, K=1152)
// Block = one image row (72 px). LDS holds rows y-1..y+1 x cols -1..80 x 136:
// stage ONCE, K-loop = LDS reads + MFMA + L2-hot B loads, no barriers, no
// global A traffic (kills the 9x tap-refetch that capped R7 at ~103 us).
__global__ __launch_bounds__(256) void halo_conv(const u16* __restrict__ A,
                                                 const u16* __restrict__ W,
                                                 const float* __restrict__ bias,
                                                 const u16* __restrict__ idn,
                                                 u16* __restrict__ out,
                                                 int relu) {
    __shared__ u16 T[3 * TROWE];   // 66912 B
    int tid = threadIdx.x;
    int bid = blockIdx.x;
    int ry = (bid & 7) * 192 + (bid >> 3);   // XCD swizzle over 1536 row-tiles
    int b = ry / 96, y = ry - b * 96;

    // zero pads: cols 74..81 (contiguous tail per tile-row) + ch-pad 128..135 per col
    for (int i = tid; i < 3 * 544; i += 256) {          // 1632 dwords
        int r = i / 544, c = i - r * 544;
        ((u32*)&T[r * TROWE + 74 * TLW])[c] = 0u;
    }
    for (int i = tid; i < 3 * 74 * 4; i += 256) {       // 888 dwords
        int r = i / 296, rem = i - r * 296;
        int col = rem >> 2, w = rem & 3;
        ((u32*)&T[r * TROWE + col * TLW + 128])[w] = 0u;
    }
    // main fill: 3 padded rows (image y-1..y+1) x 74 cols x 128 ch
    int gb = ((b * SPH + y) * SPW) * 128;   // padded row y == image row y-1
    for (int c2 = tid; c2 < 3552; c2 += 256) {
        int r = c2 / 1184, rem = c2 - r * 1184;
        int col = rem >> 4, seg = rem & 15;
        uint4 v = *(const uint4*)(A + gb + r * (SPW * 128) + col * 128 + seg * 8);
        *(uint4*)&T[r * TROWE + col * TLW + seg * 8] = v;
    }
    __syncthreads();

    int wid = tid >> 6;
    int lane = tid & 63;
    int lr = lane & 15;
    int lq = lane >> 4;
    int wn = wid * 32;
    const u16* bp0 = W + (wn + lr) * 1152 + lq * 8;
    const u16* bp1 = W + (wn + 16 + lr) * 1152 + lq * 8;

    f32x4 acc[5][2];
    #pragma unroll
    for (int i = 0; i < 5; ++i) {
        acc[i][0] = (f32x4){0.f, 0.f, 0.f, 0.f};
        acc[i][1] = (f32x4){0.f, 0.f, 0.f, 0.f};
    }

    #pragma unroll 2
    for (int it = 0; it < 36; ++it) {
        int sl = it >> 2;
        int win = (it & 3) * 32;
        int d3 = sl / 3;
        int dy = d3 - 1, dx = sl - d3 * 3 - 1;
        const u16* tb = &T[(1 + dy) * TROWE + (1 + dx + lr) * TLW + win + lq * 8];
        bf16x8 af[5], bf2[2];
        #pragma unroll
        for (int i = 0; i < 5; ++i)
            af[i] = *(const bf16x8*)(tb + i * 16 * TLW);
        bf2[0] = *(const bf16x8*)(bp0 + it * 32);
        bf2[1] = *(const bf16x8*)(bp1 + it * 32);
        #pragma unroll
        for (int i = 0; i < 5; ++i) {
            acc[i][0] = __builtin_amdgcn_mfma_f32_16x16x32_bf16(af[i], bf2[0], acc[i][0], 0, 0, 0);
            acc[i][1] = __builtin_amdgcn_mfma_f32_16x16x32_bf16(af[i], bf2[1], acc[i][1], 0, 0, 0);
        }
    }

    int obase = ((b * SPH + y + 1) * SPW + 1) * 128;
    #pragma unroll
    for (int i = 0; i < 5; ++i) {
        #pragma unroll
        for (int r = 0; r < 4; ++r) {
            int x = i * 16 + lq * 4 + r;
            if (x < 72) {
                int oa = obase + x * 128;
                #pragma unroll
                for (int j = 0; j < 2; ++j) {
                    int n = wn + j * 16 + lr;
                    float v = acc[i][j][r] + bias[n];
                    if (idn) v += b2f(idn[oa + n]);
                    if (relu) v = fmaxf(v, 0.f);
                    out[oa + n] = f2b(v);
                }
            }
        }
    }
}

// ---------------------------------------------------------------- offset conv (dilated, reads h1s with explicit zero-pad)
// R7 ping-pong structure; A staged via predicated VGPR load + ds_write (taps
// outside the image -> zeros), B via global_load_lds. Tile 128x64.
__global__ __launch_bounds__(256) void off_conv(const u16* __restrict__ A,   // h1s
                                                const u16* __restrict__ W,   // [512][1152]
                                                u16* __restrict__ out,       // [m_local][468]
                                                int dil, int m_base) {
    __shared__ u16 As[2][128 * 32];
    __shared__ u16 Bs[2][64 * 32];
    int tid = threadIdx.x;
    int wg = blockIdx.x;
    int mt = wg % 216, nt = wg / 216;
    int m0 = mt * 128, n0 = nt * 64;

    int r0 = tid >> 2;
    int q8 = (tid & 3) * 8;
    int pb2[2], py[2], px[2];
    #pragma unroll
    for (int q = 0; q < 2; ++q) {
        int p = m_base + m0 + r0 + q * 64;
        int b = p / HW6912;
        int rem = p - b * HW6912;
        pb2[q] = b;
        py[q] = rem / IMW;
        px[q] = rem - py[q] * IMW;
    }
    int brow0 = (n0 + r0) * 1152 + q8;
    int l8 = tid * 8;

    f32x4 acc[4][2];
    #pragma unroll
    for (int i = 0; i < 4; ++i) {
        acc[i][0] = (f32x4){0.f, 0.f, 0.f, 0.f};
        acc[i][1] = (f32x4){0.f, 0.f, 0.f, 0.f};
    }

    int wid = tid >> 6;
    int wm = (wid >> 1) * 64;
    int wn = (wid & 1) * 32;
    int lane = tid & 63;
    int lr = lane & 15;
    int lq = lane >> 4;

    auto stage = [&](int buf, int kt) {
        int sl = kt >> 7;
        int win = kt & 127;
        int d3 = sl / 3;
        int dy = (d3 - 1) * dil, dx = (sl - d3 * 3 - 1) * dil;
        #pragma unroll
        for (int q = 0; q < 2; ++q) {
            int y2 = py[q] + dy, x2 = px[q] + dx;
            uint4 v = make_uint4(0u, 0u, 0u, 0u);
            if (y2 >= 0 && y2 < IMH && x2 >= 0 && x2 < IMW)
                v = *(const uint4*)(A + ((pb2[q] * SPH + y2 + 1) * SPW + x2 + 1) * 128 + win + q8);
            *(uint4*)&As[buf][q * 2048 + l8] = v;
        }
        glds16(W + brow0 + kt, &Bs[buf][l8]);
    };

    stage(0, 0);
    #pragma unroll 1
    for (int it = 0; it < 36; ++it) {
        __syncthreads();
        if (it + 1 < 36) stage((it + 1) & 1, (it + 1) << 5);
        const u16* as = As[it & 1];
        const u16* bs = Bs[it & 1];
        bf16x8 af[4], bfr[2];
        #pragma unroll
        for (int i = 0; i < 4; ++i)
            af[i] = *(const bf16x8*)&as[(wm + i * 16 + lr) * 32 + lq * 8];
        #pragma unroll
        for (int j = 0; j < 2; ++j)
            bfr[j] = *(const bf16x8*)&bs[(wn + j * 16 + lr) * 32 + lq * 8];
        #pragma unroll
        for (int i = 0; i < 4; ++i)
            #pragma unroll
            for (int j = 0; j < 2; ++j)
                acc[i][j] = __builtin_amdgcn_mfma_f32_16x16x32_bf16(af[i], bfr[j], acc[i][j], 0, 0, 0);
    }

    #pragma unroll
    for (int i = 0; i < 4; ++i) {
        #pragma unroll
        for (int r = 0; r < 4; ++r) {
            int ml = m0 + wm + i * 16 + lq * 4 + r;
            int ob = ml * 468;
            #pragma unroll
            for (int j = 0; j < 2; ++j) {
                int n = n0 + wn + j * 16 + lr;
                if (n < 468) out[ob + n] = f2b(acc[i][j][r]);
            }
        }
    }
}

// ---------------------------------------------------------------- deformable conv (unchanged)
template <int F>
__device__ __forceinline__ float dsamp2(const void* sup, int base, int yi, int xi) {
    bool ok = (yi >= 0) & (yi < IMH) & (xi >= 0) & (xi < IMW);
    int yc = yi < 0 ? 0 : (yi > IMH - 1 ? IMH - 1 : yi);
    int xc = xi < 0 ? 0 : (xi > IMW - 1 ? IMW - 1 : xi);
    float v = F ? ((const float*)sup)[base + yc * IMW + xc]
                : b2f(((const u16*)sup)[base + yc * IMW + xc]);
    return ok ? v : 0.f;
}

template <int F>
__device__ __forceinline__ void deform_body(const void* __restrict__ sup,
                                            const u16* __restrict__ oc,
                                            const float* __restrict__ wsm,
                                            f32x4 acc[7],
                                            int c0, int c1, int b, int y, int x, int dil) {
    #pragma unroll 1
    for (int c = c0; c < c1; ++c) {
        int ibase = (b * CIN + c) * HW6912;
        #pragma unroll
        for (int t = 0; t < 9; ++t) {
            u32 pr = *(const u32*)(oc + c * 18 + t * 2);
            float dy = b2f((u16)(pr & 0xffffu));
            float dx = b2f((u16)(pr >> 16));
            float py = (float)(y + (t / 3 - 1) * dil) + dy;
            float px = (float)(x + (t % 3 - 1) * dil) + dx;
            float y0f = floorf(py), x0f = floorf(px);
            float ly = py - y0f, lx = px - x0f;
            int y0 = (int)y0f, x0 = (int)x0f;
            float v00 = dsamp2<F>(sup, ibase, y0, x0);
            float v01 = dsamp2<F>(sup, ibase, y0, x0 + 1);
            float v10 = dsamp2<F>(sup, ibase, y0 + 1, x0);
            float v11 = dsamp2<F>(sup, ibase, y0 + 1, x0 + 1);
            float val = (v00 * (1.f - lx) + v01 * lx) * (1.f - ly)
                      + (v10 * (1.f - lx) + v11 * lx) * ly;
            const float4* wr = (const float4*)&wsm[(c * 9 + t) * 28];
            #pragma unroll
            for (int u = 0; u < 7; ++u) {
                float4 w4 = wr[u];
                acc[u][0] = fmaf(val, w4.x, acc[u][0]);
                acc[u][1] = fmaf(val, w4.y, acc[u][1]);
                acc[u][2] = fmaf(val, w4.z, acc[u][2]);
                acc[u][3] = fmaf(val, w4.w, acc[u][3]);
            }
        }
    }
}

__global__ __launch_bounds__(256) void deform_kernel(const void* __restrict__ sup,
                                                     const u16* __restrict__ offb,
                                                     const void* __restrict__ dwall,
                                                     int dwoff,
                                                     float* __restrict__ accws,
                                                     int dil, int first, int m_base,
                                                     const int* __restrict__ flag) {
    int f = *flag;
    __shared__ float wsm[26 * 9 * 28];
    __shared__ float red[4 * 64 * 27];
    int tid = threadIdx.x;
    for (int i = tid; i < 26 * 9 * 28; i += 256) {
        int o = i % 28;
        int ct = i / 28;
        int c = ct / 9, t = ct - c * 9;
        wsm[i] = (o < CIN) ? ldin(dwall, dwoff + (o * CIN + c) * 9 + t, f) : 0.f;
    }
    __syncthreads();

    int px = tid & 63;
    int cg = tid >> 6;
    int c0 = (cg * 26) >> 2;
    int c1 = ((cg + 1) * 26) >> 2;
    int ml = blockIdx.x * 64 + px;
    int m = m_base + ml;
    int b = m / HW6912;
    int p = m - b * HW6912;
    int y = p / IMW;
    int x = p - y * IMW;

    f32x4 acc[7];
    #pragma unroll
    for (int u = 0; u < 7; ++u) acc[u] = (f32x4){0.f, 0.f, 0.f, 0.f};

    const u16* oc = offb + (size_t)ml * 468;
    if (f) deform_body<1>(sup, oc, wsm, acc, c0, c1, b, y, x, dil);
    else   deform_body<0>(sup, oc, wsm, acc, c0, c1, b, y, x, dil);

    float* myred = red + tid * 27;
    #pragma unroll
    for (int u = 0; u < 7; ++u) {
        #pragma unroll
        for (int k2 = 0; k2 < 4; ++k2) {
            int o = u * 4 + k2;
            if (o < 26) myred[o] = acc[u][k2];
        }
    }
    __syncthreads();

    int base_m = m_base + blockIdx.x * 64;
    for (int v = tid; v < 64 * 26; v += 256) {
        int ppx = v / 26;
        int o = v - ppx * 26;
        float s = red[ppx * 27 + o] + red[(64 + ppx) * 27 + o]
                + red[(128 + ppx) * 27 + o] + red[(192 + ppx) * 27 + o];
        size_t ai = (size_t)(base_m + ppx) * 32 + o;
        if (first) accws[ai] = s;
        else       accws[ai] += s;
    }
}

// ---------------------------------------------------------------- finalize
__global__ __launch_bounds__(256) void finalize_kernel(const float* __restrict__ accws,
                                                       void* __restrict__ out,
                                                       const int* __restrict__ flag) {
    int f = *flag;
    int q = blockIdx.x * 256 + threadIdx.x;
    int b = q / (CIN * HW6912);
    int r = q - b * (CIN * HW6912);
    int o = r / HW6912;
    int p = r - o * HW6912;
    float v = accws[(size_t)(b * HW6912 + p) * 32 + o] * 0.2f;
    if (f) ((float*)out)[q] = v;
    else   ((u16*)out)[q] = f2b(v);
}

// ---------------------------------------------------------------- host
extern "C" void kernel_launch(void* const* d_in, const int* in_sizes, int n_in,
                              void* d_out, int out_size, void* d_ws, size_t ws_size,
                              hipStream_t stream) {
    (void)in_sizes; (void)n_in; (void)out_size;
    const void* ref_x    = d_in[0];
    const void* sup_x    = d_in[1];
    const void* w1_0     = d_in[2];
    const void* w2_0     = d_in[3];
    const void* wd_0     = d_in[4];
    const void* bn1_0    = d_in[5];
    const void* bn2_0    = d_in[6];
    const void* bnd_0    = d_in[7];
    const void* w1_rest  = d_in[8];
    const void* w2_rest  = d_in[9];
    const void* bn1_rest = d_in[10];
    const void* bn2_rest = d_in[11];
    const void* offset_w = d_in[12];
    const void* deform_w = d_in[13];

    // workspace layout (bytes) — total 98.5 MB (proven budget >= 139.6 MB)
    size_t o_x0    = 0;                          // 16*98*74*32*2   =  7,426,048
    size_t o_h0    = o_x0 + 7426048;             // 16*98*74*128*2  = 29,704,192 (offb aliases)
    size_t o_h1s   = o_h0 + 29704192;            // 29,704,192
    size_t o_acc   = o_h1s + 29704192;           // 14,155,776
    size_t o_wrest = o_acc + 14155776;           // 11,206,656
    size_t o_w20   = o_wrest + 11206656;         //    294,912
    size_t o_w10   = o_w20 + 294912;             //     73,728
    size_t o_wd    = o_w10 + 73728;              //      8,192
    size_t o_woff  = o_wd + 8192;                //  5,898,240
    size_t o_bias  = o_woff + 5898240;           //     20,992
    size_t o_flag  = o_bias + 20992;             //         64
    size_t o_end   = o_flag + 64;                // 98,492,992
    if (ws_size < o_end) return;

    char* ws = (char*)d_ws;
    u16* x0    = (u16*)(ws + o_x0);
    u16* h0    = (u16*)(ws + o_h0);
    u16* offb  = (u16*)(ws + o_h0);      // alias: h0 dead once the chain finishes
    u16* h1s   = (u16*)(ws + o_h1s);
    float* accb = (float*)(ws + o_acc);
    u16* Wr    = (u16*)(ws + o_wrest);
    u16* W20   = (u16*)(ws + o_w20);
    u16* W10   = (u16*)(ws + o_w10);
    u16* Wd    = (u16*)(ws + o_wd);
    u16* Woff  = (u16*)(ws + o_woff);
    float* biasb = (float*)(ws + o_bias);
    int* flagp = (int*)(ws + o_flag);

    dim3 blk(256);

    probe_kernel<<<1, 64, 0, stream>>>(bn1_0, flagp);
    // zero x0 + h0 + h1s (padding halos must be zero)
    zero_ws_kernel<<<2048, blk, 0, stream>>>((uint4*)ws, (int)((7426048 + 2 * 29704192) / 16));
    fill_x0_kernel<<<432, blk, 0, stream>>>(ref_x, sup_x, x0, flagp);
    prep_rest_kernel<<<21888, blk, 0, stream>>>(w1_rest, w2_rest, bn1_rest, bn2_rest, Wr, flagp);
    prep_b0_kernel<<<736, blk, 0, stream>>>(w1_0, w2_0, wd_0, bn1_0, bn2_0, bnd_0, W20, W10, Wd, flagp);
    prep_off_kernel<<<11520, blk, 0, stream>>>(offset_w, Woff, flagp);
    prep_bias_kernel<<<21, blk, 0, stream>>>(bn1_0, bn2_0, bnd_0, bn1_rest, bn2_rest, biasb, flagp);

    // block0: downsample (1x1 conv + BN) x0 -> h1s ; conv1 x0 -> h0
    conv_gemm<<<dim3(864, 2), blk, 0, stream>>>(x0, Wd, biasb + 2 * 128, h1s, 5, 1, 32, 0);
    conv_gemm<<<dim3(864, 2), blk, 0, stream>>>(x0, W10, biasb + 0 * 128, h0, 5, 9, 288, 1);
    // block0: conv2 + BN + idn(h1s) + relu -> h1s
    halo_conv<<<1536, blk, 0, stream>>>(h0, W20, biasb + 1 * 128, h1s, h1s, 1);

    for (int t = 0; t < 19; ++t) {
        const u16* wa = Wr + (size_t)t * 147456;
        const u16* wb = Wr + (size_t)(19 + t) * 147456;
        halo_conv<<<1536, blk, 0, stream>>>(h1s, wa, biasb + (3 + t) * 128, nullptr, h0, 1);
        halo_conv<<<1536, blk, 0, stream>>>(h0, wb, biasb + (22 + t) * 128, h1s, h1s, 1);
    }

    // 5 dilation branches, chunked over 4 batches (offb aliases h0)
    const int dils[5] = {3, 6, 12, 18, 24};
    for (int i = 0; i < 5; ++i) {
        for (int cb = 0; cb < 4; ++cb) {
            int mb = cb * 27648;
            off_conv<<<1728, blk, 0, stream>>>(h1s, Woff + (size_t)i * 589824, offb, dils[i], mb);
            deform_kernel<<<432, blk, 0, stream>>>(sup_x, offb, deform_w, i * 6084, accb,
                                                   dils[i], (i == 0) ? 1 : 0, mb, flagp);
        }
    }
    finalize_kernel<<<11232, blk, 0, stream>>>(accb, d_out, flagp);
}